// Round 7
// baseline (116.159 us; speedup 1.0000x reference)
//
#include <hip/hip_runtime.h>
#include <stdint.h>

// FMFMNeuron LIF scan, 4-phase with EXACT speculative T-chunking:
//  1) compress: 134MB f32 spikes -> 4MB 2-bit cur-codes [T/16][B]
//  2) scanA (parallel): C=16 chunks x B neurons; each chunk warms up 512 steps
//     from mem=0 (chunks 0..2: warmup clamped to t=0 => exact), runs its
//     256-step body, emits spike bits + (start,end) states to spec[].
//  3) scanB (sequential per neuron, parallel over neurons): chain chunks by
//     bit-comparing true state vs spec start; match -> adopt spec end;
//     mismatch -> recompute the 256-step chunk exactly + patch bits.
//     => output is bit-exact REGARDLESS of speculation quality.
//  4) expand: 2MB bits -> 67MB f32 output.
//
// Step math (absmax=0 through rounds 1..6): spikes in {0,1} =>
//   cur in {0, w1, w2, fadd(w1,w2)} exactly; strict left-to-right:
//   m = fsub(fadd(fmul(0.95f,mem), cur), rst); spk = m>1.0f; rst' = spk.

#define T_STEPS 4096
#define B_NEUR  4096
#define NCHUNK  16
#define CH_LEN  256                    // steps per chunk
#define CH_W    16                     // code words per chunk body
#define WARM_W  32                     // warmup words (512 steps)
#define KG      (T_STEPS / 16)         // 256 code words per neuron
#define NWORDS  (T_STEPS / 32)         // 128 packed spike words per neuron

// ---- phase 1: compress spikes to 2-bit codes (float4 = 2 neurons/step) -----
__global__ __launch_bounds__(256) void fmfm_compress(
    const float4* __restrict__ sp4,    // [T][B/2] float4
    uint32_t*     __restrict__ codes)  // [T/16][B]
{
    const int tid = blockIdx.x * 256 + threadIdx.x;   // 0 .. 512K-1
    const int b2  = tid & (B_NEUR / 2 - 1);           // neuron pair
    const int kg  = tid >> 11;                        // 0..255
    const float4* p = sp4 + (size_t)kg * 16 * (B_NEUR / 2) + b2;
    uint32_t we = 0, wo = 0;
    #pragma unroll
    for (int i = 0; i < 16; ++i) {
        float4 s = p[(size_t)i * (B_NEUR / 2)];
        uint32_t ce = (s.x != 0.0f ? 1u : 0u) | (s.y != 0.0f ? 2u : 0u);
        uint32_t co = (s.z != 0.0f ? 1u : 0u) | (s.w != 0.0f ? 2u : 0u);
        we |= ce << (2 * i);
        wo |= co << (2 * i);
    }
    uint2 wv = make_uint2(we, wo);
    *reinterpret_cast<uint2*>(codes + (size_t)kg * B_NEUR + 2 * b2) = wv;
}

// shared step macro
#define STEP1(CUR, POS)                                                   \
    {                                                                     \
        float _m = __fsub_rn(__fadd_rn(__fmul_rn(0.95f, mem), (CUR)),     \
                             rst);                                        \
        uint32_t _sb = (_m > 1.0f) ? 1u : 0u;                             \
        bits |= _sb << (POS);                                             \
        rst = _sb ? 1.0f : 0.0f;                                          \
        mem = _m;                                                         \
    }

// ---- phase 2: parallel speculative chunk scan ------------------------------
__global__ __launch_bounds__(256) void fmfm_scanA(
    const uint32_t* __restrict__ codes,    // [T/16][B]
    const float*    __restrict__ W,
    uint32_t*       __restrict__ bits_out, // [T/32][B]
    uint4*          __restrict__ spec)     // [C][B]: start/end states
{
    __shared__ float2 lut2[16];   // nibble -> 2 exact cur values (32 banks, conflict-free)

    const float w1  = W[0];
    const float w2  = W[1];
    const float w12 = __fadd_rn(w1, w2);

    if (threadIdx.x < 16) {
        uint32_t e = threadIdx.x;
        uint32_t c0 = e & 3u, c1 = (e >> 2) & 3u;
        float2 v;
        v.x = (c0 & 1u) ? ((c0 & 2u) ? w12 : w1) : ((c0 & 2u) ? w2 : 0.0f);
        v.y = (c1 & 1u) ? ((c1 & 2u) ? w12 : w1) : ((c1 & 2u) ? w2 : 0.0f);
        lut2[e] = v;
    }
    __syncthreads();

    const int tid = blockIdx.x * 256 + threadIdx.x;   // 0..65535
    const int b   = tid & (B_NEUR - 1);
    const int c   = tid >> 12;                        // chunk 0..15
    const int body_w0 = c * CH_W;                     // first body word (even)
    const int w_start = (body_w0 >= WARM_W) ? body_w0 - WARM_W : 0;
    const int w_end   = body_w0 + CH_W;               // exclusive
    const int nw      = w_end - w_start;              // 16/32/48 (even)
    const uint32_t* cp = codes + b;

#define CLD(IDX) cp[(size_t)((IDX) < w_end ? (IDX) : (w_end - 1)) * B_NEUR]

#define DECODE2(WORD, D)                                                  \
    {                                                                     \
        _Pragma("unroll")                                                 \
        for (int _j = 0; _j < 8; ++_j)                                    \
            D[_j] = lut2[((WORD) >> (4 * _j)) & 0xFu];                    \
    }

#define CHAIN16(D, HALF)                                                  \
    {                                                                     \
        _Pragma("unroll")                                                 \
        for (int _j = 0; _j < 8; ++_j) {                                  \
            STEP1(D[_j].x, ((HALF) << 4) + 2 * _j)                        \
            STEP1(D[_j].y, ((HALF) << 4) + 2 * _j + 1)                    \
        }                                                                 \
    }

    uint32_t pa = CLD(w_start);
    uint32_t pb = CLD(w_start + 1);
    uint32_t pc = CLD(w_start + 2);
    uint32_t pd = CLD(w_start + 3);

    float2 dA[8], dB[8];
    DECODE2(pa, dA)

    float mem = 0.0f, rst = 0.0f;
    float sm = 0.0f, sr = 0.0f;
    uint32_t bits = 0;

    for (int iw = 0; iw < nw; iw += 2) {
        const int widx = w_start + iw;            // even (scalar-uniform)
        // -------- A body: word widx (even) --------
        uint32_t t0 = CLD(widx + 4);
        DECODE2(pb, dB)                           // decode word widx+1
        if (widx == body_w0) { sm = mem; sr = rst; bits = 0; }
        CHAIN16(dA, 0)
        pa = pb; pb = pc; pc = pd; pd = t0;
        // -------- B body: word widx+1 (odd) --------
        uint32_t t1 = CLD(widx + 5);
        DECODE2(pb, dA)                           // decode word widx+2
        CHAIN16(dB, 1)
        if (widx + 1 > body_w0) {
            bits_out[(size_t)((widx + 1) >> 1) * B_NEUR + b] = bits;
            bits = 0;
        }
        pa = pb; pb = pc; pc = pd; pd = t1;
    }

    uint4 sv;
    sv.x = __float_as_uint(sm);
    sv.y = (sr != 0.0f) ? 1u : 0u;
    sv.z = __float_as_uint(mem);
    sv.w = (rst != 0.0f) ? 1u : 0u;
    spec[(size_t)c * B_NEUR + b] = sv;

#undef CLD
#undef DECODE2
#undef CHAIN16
}

// ---- phase 3: exact chaining / verification --------------------------------
__global__ __launch_bounds__(64) void fmfm_scanB(
    const uint32_t* __restrict__ codes,
    const float*    __restrict__ W,
    uint32_t*       __restrict__ bits_out,
    const uint4*    __restrict__ spec)
{
    const int b = blockIdx.x * 64 + threadIdx.x;
    const float w1  = W[0];
    const float w2  = W[1];
    const float w12 = __fadd_rn(w1, w2);

    float mem = 0.0f, rst = 0.0f;
    for (int c = 0; c < NCHUNK; ++c) {
        uint4 s = spec[(size_t)c * B_NEUR + b];
        bool ok = (s.x == __float_as_uint(mem)) &&
                  ((s.y != 0u) == (rst != 0.0f));
        if (ok) {
            mem = __uint_as_float(s.z);
            rst = s.w ? 1.0f : 0.0f;
        } else {
            // rare: recompute chunk c exactly from true state, patch bits
            uint32_t bits = 0;
            for (int wi = 0; wi < CH_W; ++wi) {
                uint32_t w = codes[(size_t)(c * CH_W + wi) * B_NEUR + b];
                #pragma unroll
                for (int j = 0; j < 16; ++j) {
                    uint32_t cc = (w >> (2 * j)) & 3u;
                    float cur = (cc & 1u) ? ((cc & 2u) ? w12 : w1)
                                          : ((cc & 2u) ? w2 : 0.0f);
                    STEP1(cur, (((wi & 1) << 4) + j))
                }
                if (wi & 1) {
                    bits_out[(size_t)((c * CH_W + wi) >> 1) * B_NEUR + b] = bits;
                    bits = 0;
                }
            }
        }
    }
}

// ---- phase 4: expand bits to f32 (proven) ----------------------------------
__global__ __launch_bounds__(256) void fmfm_expand(
    const uint32_t* __restrict__ bits,  // [T/32][B]
    float*          __restrict__ out)   // [T][B]
{
    const int tid = blockIdx.x * 256 + threadIdx.x;  // 0..131071
    const int b4  = tid & 1023;
    const int w   = tid >> 10;
    const uint4 wv = *reinterpret_cast<const uint4*>(
        bits + (size_t)w * B_NEUR + (size_t)b4 * 4);
    float4* o = reinterpret_cast<float4*>(
        out + (size_t)w * 32 * B_NEUR + (size_t)b4 * 4);
    #pragma unroll
    for (int j = 0; j < 32; ++j) {
        float4 v;
        v.x = ((wv.x >> j) & 1u) ? 1.0f : 0.0f;
        v.y = ((wv.y >> j) & 1u) ? 1.0f : 0.0f;
        v.z = ((wv.z >> j) & 1u) ? 1.0f : 0.0f;
        v.w = ((wv.w >> j) & 1u) ? 1.0f : 0.0f;
        o[(size_t)j * (B_NEUR / 4)] = v;
    }
}

// ---- fallback: round-1 proven fused kernel (if ws too small) ---------------
__global__ __launch_bounds__(64) void fmfm_scan_fused(
    const float2* __restrict__ sp, const float* __restrict__ W,
    float* __restrict__ out)
{
    const int b = blockIdx.x * 64 + threadIdx.x;
    const float w1 = W[0];
    const float w2 = W[1];
    const float2* p = sp + b;
    float* q = out + b;
    float mem = 0.0f, rst = 0.0f;
    #pragma unroll 8
    for (int t = 0; t < T_STEPS; ++t) {
        float2 s = p[(size_t)t * B_NEUR];
        float cur = __fadd_rn(__fmul_rn(s.x, w1), __fmul_rn(s.y, w2));
        float m = __fsub_rn(__fadd_rn(__fmul_rn(0.95f, mem), cur), rst);
        float spk = (m > 1.0f) ? 1.0f : 0.0f;
        q[(size_t)t * B_NEUR] = spk;
        mem = m;
        rst = spk;
    }
}

extern "C" void kernel_launch(void* const* d_in, const int* in_sizes, int n_in,
                              void* d_out, int out_size, void* d_ws, size_t ws_size,
                              hipStream_t stream) {
    const float4* sp4 = (const float4*)d_in[0];
    const float*  W   = (const float*)d_in[1];
    float*        out = (float*)d_out;

    const size_t codes_bytes = (size_t)KG * B_NEUR * 4;          // 4MB
    const size_t bits_bytes  = (size_t)NWORDS * B_NEUR * 4;      // 2MB
    const size_t spec_bytes  = (size_t)NCHUNK * B_NEUR * 16;     // 1MB
    if (ws_size < codes_bytes + bits_bytes + spec_bytes) {
        fmfm_scan_fused<<<dim3(B_NEUR / 64), dim3(64), 0, stream>>>(
            (const float2*)d_in[0], W, out);
        return;
    }
    uint32_t* codes = (uint32_t*)d_ws;
    uint32_t* bits  = (uint32_t*)((char*)d_ws + codes_bytes);
    uint4*    spec  = (uint4*)((char*)d_ws + codes_bytes + bits_bytes);

    fmfm_compress<<<dim3(KG * (B_NEUR / 2) / 256), dim3(256), 0, stream>>>(sp4, codes);
    fmfm_scanA<<<dim3(NCHUNK * B_NEUR / 256), dim3(256), 0, stream>>>(codes, W, bits, spec);
    fmfm_scanB<<<dim3(B_NEUR / 64), dim3(64), 0, stream>>>(codes, W, bits, spec);
    fmfm_expand<<<dim3(NWORDS * (B_NEUR / 4) / 256), dim3(256), 0, stream>>>(bits, out);
}

// Round 8
// 60.792 us; speedup vs baseline: 1.9108x; 1.9108x over previous
//
#include <hip/hip_runtime.h>
#include <stdint.h>

// FMFMNeuron LIF scan, 4-phase with EXACT speculative T-chunking:
//  1) compress: 134MB f32 spikes -> 4MB 2-bit cur-codes [T/16][B]
//  2) scanA (parallel): C=16 chunks x B neurons; each chunk warms up 768 steps
//     from mem=0 (chunks 0..2: warmup clamped to t=0 => exact), runs its
//     256-step body, emits spike bits + (start,end) states to spec[].
//     768 warmup: diff enters the last-400-step window at ~2e-8 < 0.5ulp(1.0)
//     => trajectories bit-converge before the body with ~0 flip risk.
//  3) scanB: chain chunks by bit-comparing true state vs spec start;
//     match -> adopt spec end; mismatch -> recompute chunk exactly + patch.
//     Output is bit-exact REGARDLESS of speculation quality.
//  4) expand: 2MB bits -> 67MB f32 output.
//
// Step math (absmax=0 through rounds 1..7): spikes in {0,1} =>
//   cur in {0, w1, w2, fadd(w1,w2)} exactly; strict left-to-right:
//   m = fsub(fadd(fmul(0.95f,mem), cur), rst); spk = m>1.0f; rst' = spk.

#define T_STEPS 4096
#define B_NEUR  4096
#define NCHUNK  16
#define CH_W    16                     // code words per chunk body
#define WARM_W  48                     // warmup words (768 steps)
#define KG      (T_STEPS / 16)         // 256 code words per neuron
#define NWORDS  (T_STEPS / 32)         // 128 packed spike words per neuron

// ---- phase 1: compress spikes to 2-bit codes (float4 = 2 neurons/step) -----
__global__ __launch_bounds__(256) void fmfm_compress(
    const float4* __restrict__ sp4,    // [T][B/2] float4
    uint32_t*     __restrict__ codes)  // [T/16][B]
{
    const int tid = blockIdx.x * 256 + threadIdx.x;   // 0 .. 512K-1
    const int b2  = tid & (B_NEUR / 2 - 1);           // neuron pair
    const int kg  = tid >> 11;                        // 0..255
    const float4* p = sp4 + (size_t)kg * 16 * (B_NEUR / 2) + b2;
    uint32_t we = 0, wo = 0;
    #pragma unroll
    for (int i = 0; i < 16; ++i) {
        float4 s = p[(size_t)i * (B_NEUR / 2)];
        uint32_t ce = (s.x != 0.0f ? 1u : 0u) | (s.y != 0.0f ? 2u : 0u);
        uint32_t co = (s.z != 0.0f ? 1u : 0u) | (s.w != 0.0f ? 2u : 0u);
        we |= ce << (2 * i);
        wo |= co << (2 * i);
    }
    uint2 wv = make_uint2(we, wo);
    *reinterpret_cast<uint2*>(codes + (size_t)kg * B_NEUR + 2 * b2) = wv;
}

// shared step macro
#define STEP1(CUR, POS)                                                   \
    {                                                                     \
        float _m = __fsub_rn(__fadd_rn(__fmul_rn(0.95f, mem), (CUR)),     \
                             rst);                                        \
        uint32_t _sb = (_m > 1.0f) ? 1u : 0u;                             \
        bits |= _sb << (POS);                                             \
        rst = _sb ? 1.0f : 0.0f;                                          \
        mem = _m;                                                         \
    }

// ---- phase 2: parallel speculative chunk scan ------------------------------
__global__ __launch_bounds__(256) void fmfm_scanA(
    const uint32_t* __restrict__ codes,    // [T/16][B]
    const float*    __restrict__ W,
    uint32_t*       __restrict__ bits_out, // [T/32][B]
    uint4*          __restrict__ spec)     // [C][B]: start/end states
{
    __shared__ float2 lut2[16];   // nibble -> 2 exact cur values (conflict-free)

    const float w1  = W[0];
    const float w2  = W[1];
    const float w12 = __fadd_rn(w1, w2);

    if (threadIdx.x < 16) {
        uint32_t e = threadIdx.x;
        uint32_t c0 = e & 3u, c1 = (e >> 2) & 3u;
        float2 v;
        v.x = (c0 & 1u) ? ((c0 & 2u) ? w12 : w1) : ((c0 & 2u) ? w2 : 0.0f);
        v.y = (c1 & 1u) ? ((c1 & 2u) ? w12 : w1) : ((c1 & 2u) ? w2 : 0.0f);
        lut2[e] = v;
    }
    __syncthreads();

    const int tid = blockIdx.x * 256 + threadIdx.x;   // 0..65535
    const int b   = tid & (B_NEUR - 1);
    const int c   = tid >> 12;                        // chunk 0..15
    const int body_w0 = c * CH_W;                     // first body word (even)
    const int w_start = (body_w0 >= WARM_W) ? body_w0 - WARM_W : 0;
    const int w_end   = body_w0 + CH_W;               // exclusive
    const int nw      = w_end - w_start;              // 16/32/48/64 (even)
    const uint32_t* cp = codes + b;

#define CLD(IDX) cp[(size_t)((IDX) < w_end ? (IDX) : (w_end - 1)) * B_NEUR]

#define DECODE2(WORD, D)                                                  \
    {                                                                     \
        _Pragma("unroll")                                                 \
        for (int _j = 0; _j < 8; ++_j)                                    \
            D[_j] = lut2[((WORD) >> (4 * _j)) & 0xFu];                    \
    }

#define CHAIN16(D, HALF)                                                  \
    {                                                                     \
        _Pragma("unroll")                                                 \
        for (int _j = 0; _j < 8; ++_j) {                                  \
            STEP1(D[_j].x, ((HALF) << 4) + 2 * _j)                        \
            STEP1(D[_j].y, ((HALF) << 4) + 2 * _j + 1)                    \
        }                                                                 \
    }

    uint32_t pa = CLD(w_start);
    uint32_t pb = CLD(w_start + 1);
    uint32_t pc = CLD(w_start + 2);
    uint32_t pd = CLD(w_start + 3);

    float2 dA[8], dB[8];
    DECODE2(pa, dA)

    float mem = 0.0f, rst = 0.0f;
    float sm = 0.0f, sr = 0.0f;
    uint32_t bits = 0;

    for (int iw = 0; iw < nw; iw += 2) {
        const int widx = w_start + iw;            // even
        // -------- A body: word widx (even) --------
        uint32_t t0 = CLD(widx + 4);
        DECODE2(pb, dB)                           // decode word widx+1
        if (widx == body_w0) { sm = mem; sr = rst; bits = 0; }
        CHAIN16(dA, 0)
        pa = pb; pb = pc; pc = pd; pd = t0;
        // -------- B body: word widx+1 (odd) --------
        uint32_t t1 = CLD(widx + 5);
        DECODE2(pb, dA)                           // decode word widx+2
        CHAIN16(dB, 1)
        if (widx + 1 > body_w0) {
            bits_out[(size_t)((widx + 1) >> 1) * B_NEUR + b] = bits;
            bits = 0;
        }
        pa = pb; pb = pc; pc = pd; pd = t1;
    }

    uint4 sv;
    sv.x = __float_as_uint(sm);
    sv.y = (sr != 0.0f) ? 1u : 0u;
    sv.z = __float_as_uint(mem);
    sv.w = (rst != 0.0f) ? 1u : 0u;
    spec[(size_t)c * B_NEUR + b] = sv;

#undef CLD
#undef DECODE2
#undef CHAIN16
}

// ---- phase 3: exact chaining / verification --------------------------------
__global__ __launch_bounds__(64) void fmfm_scanB(
    const uint32_t* __restrict__ codes,
    const float*    __restrict__ W,
    uint32_t*       __restrict__ bits_out,
    const uint4*    __restrict__ spec)
{
    const int b = blockIdx.x * 64 + threadIdx.x;
    const float w1  = W[0];
    const float w2  = W[1];
    const float w12 = __fadd_rn(w1, w2);

    // preload all 16 spec records (static indexing -> stays in VGPRs;
    // all loads issue before the compare chain begins)
    uint4 sv[NCHUNK];
    #pragma unroll
    for (int c = 0; c < NCHUNK; ++c)
        sv[c] = spec[(size_t)c * B_NEUR + b];

    float mem = 0.0f, rst = 0.0f;
    #pragma unroll
    for (int c = 0; c < NCHUNK; ++c) {
        uint4 s = sv[c];
        bool ok = (s.x == __float_as_uint(mem)) &&
                  ((s.y != 0u) == (rst != 0.0f));
        if (ok) {
            mem = __uint_as_float(s.z);
            rst = s.w ? 1.0f : 0.0f;
        } else {
            // rare: recompute chunk c exactly from true state, patch bits
            uint32_t bits = 0;
            for (int wi = 0; wi < CH_W; ++wi) {
                uint32_t w = codes[(size_t)(c * CH_W + wi) * B_NEUR + b];
                #pragma unroll
                for (int j = 0; j < 16; ++j) {
                    uint32_t cc = (w >> (2 * j)) & 3u;
                    float cur = (cc & 1u) ? ((cc & 2u) ? w12 : w1)
                                          : ((cc & 2u) ? w2 : 0.0f);
                    STEP1(cur, (((wi & 1) << 4) + j))
                }
                if (wi & 1) {
                    bits_out[(size_t)((c * CH_W + wi) >> 1) * B_NEUR + b] = bits;
                    bits = 0;
                }
            }
        }
    }
}

// ---- phase 4: expand bits to f32 (proven) ----------------------------------
__global__ __launch_bounds__(256) void fmfm_expand(
    const uint32_t* __restrict__ bits,  // [T/32][B]
    float*          __restrict__ out)   // [T][B]
{
    const int tid = blockIdx.x * 256 + threadIdx.x;  // 0..131071
    const int b4  = tid & 1023;
    const int w   = tid >> 10;
    const uint4 wv = *reinterpret_cast<const uint4*>(
        bits + (size_t)w * B_NEUR + (size_t)b4 * 4);
    float4* o = reinterpret_cast<float4*>(
        out + (size_t)w * 32 * B_NEUR + (size_t)b4 * 4);
    #pragma unroll
    for (int j = 0; j < 32; ++j) {
        float4 v;
        v.x = ((wv.x >> j) & 1u) ? 1.0f : 0.0f;
        v.y = ((wv.y >> j) & 1u) ? 1.0f : 0.0f;
        v.z = ((wv.z >> j) & 1u) ? 1.0f : 0.0f;
        v.w = ((wv.w >> j) & 1u) ? 1.0f : 0.0f;
        o[(size_t)j * (B_NEUR / 4)] = v;
    }
}

// ---- fallback: round-1 proven fused kernel (if ws too small) ---------------
__global__ __launch_bounds__(64) void fmfm_scan_fused(
    const float2* __restrict__ sp, const float* __restrict__ W,
    float* __restrict__ out)
{
    const int b = blockIdx.x * 64 + threadIdx.x;
    const float w1 = W[0];
    const float w2 = W[1];
    const float2* p = sp + b;
    float* q = out + b;
    float mem = 0.0f, rst = 0.0f;
    #pragma unroll 8
    for (int t = 0; t < T_STEPS; ++t) {
        float2 s = p[(size_t)t * B_NEUR];
        float cur = __fadd_rn(__fmul_rn(s.x, w1), __fmul_rn(s.y, w2));
        float m = __fsub_rn(__fadd_rn(__fmul_rn(0.95f, mem), cur), rst);
        float spk = (m > 1.0f) ? 1.0f : 0.0f;
        q[(size_t)t * B_NEUR] = spk;
        mem = m;
        rst = spk;
    }
}

extern "C" void kernel_launch(void* const* d_in, const int* in_sizes, int n_in,
                              void* d_out, int out_size, void* d_ws, size_t ws_size,
                              hipStream_t stream) {
    const float4* sp4 = (const float4*)d_in[0];
    const float*  W   = (const float*)d_in[1];
    float*        out = (float*)d_out;

    const size_t codes_bytes = (size_t)KG * B_NEUR * 4;          // 4MB
    const size_t bits_bytes  = (size_t)NWORDS * B_NEUR * 4;      // 2MB
    const size_t spec_bytes  = (size_t)NCHUNK * B_NEUR * 16;     // 1MB
    if (ws_size < codes_bytes + bits_bytes + spec_bytes) {
        fmfm_scan_fused<<<dim3(B_NEUR / 64), dim3(64), 0, stream>>>(
            (const float2*)d_in[0], W, out);
        return;
    }
    uint32_t* codes = (uint32_t*)d_ws;
    uint32_t* bits  = (uint32_t*)((char*)d_ws + codes_bytes);
    uint4*    spec  = (uint4*)((char*)d_ws + codes_bytes + bits_bytes);

    fmfm_compress<<<dim3(KG * (B_NEUR / 2) / 256), dim3(256), 0, stream>>>(sp4, codes);
    fmfm_scanA<<<dim3(NCHUNK * B_NEUR / 256), dim3(256), 0, stream>>>(codes, W, bits, spec);
    fmfm_scanB<<<dim3(B_NEUR / 64), dim3(64), 0, stream>>>(codes, W, bits, spec);
    fmfm_expand<<<dim3(NWORDS * (B_NEUR / 4) / 256), dim3(256), 0, stream>>>(bits, out);
}

// Round 9
// 54.930 us; speedup vs baseline: 2.1147x; 1.1067x over previous
//
#include <hip/hip_runtime.h>
#include <stdint.h>

// FMFMNeuron LIF scan, 3-phase with EXACT speculative T-chunking:
//  1) compress: 134MB f32 spikes -> 4MB 2-bit cur-codes [T/16][B] (nt loads)
//  2) scanA (parallel): C=16 chunks x B neurons; 768-step warmup from mem=0
//     (chunks 0..2 clamped => exact), then 256-step body writing f32 spikes
//     DIRECTLY to out (nt stores) + (start,end) states to spec[].
//  3) scanB: chain chunks by bit-comparing true state vs spec start;
//     match -> adopt spec end; mismatch -> recompute chunk exactly, patch out.
//     Output is bit-exact REGARDLESS of speculation quality.
//
// Step math (absmax=0 through rounds 1..8): spikes in {0,1} =>
//   cur in {0, w1, w2, fadd(w1,w2)} exactly; strict left-to-right:
//   m = fsub(fadd(fmul(0.95f,mem), cur), rst); spk = m>1.0f; rst' = spk.

#define T_STEPS 4096
#define B_NEUR  4096
#define NCHUNK  16
#define CH_W    16                     // code words per chunk body
#define WARM_W  48                     // warmup words (768 steps)
#define KG      (T_STEPS / 16)         // 256 code words per neuron

typedef float f4v __attribute__((ext_vector_type(4)));

// ---- phase 1: compress spikes to 2-bit codes (nt float4 loads) -------------
__global__ __launch_bounds__(256) void fmfm_compress(
    const f4v*  __restrict__ sp4,      // [T][B/2] float4
    uint32_t*   __restrict__ codes)    // [T/16][B]
{
    const int tid = blockIdx.x * 256 + threadIdx.x;   // 0 .. 512K-1
    const int b2  = tid & (B_NEUR / 2 - 1);           // neuron pair
    const int kg  = tid >> 11;                        // 0..255
    const f4v* p = sp4 + (size_t)kg * 16 * (B_NEUR / 2) + b2;
    uint32_t we = 0, wo = 0;
    #pragma unroll
    for (int i = 0; i < 16; ++i) {
        f4v s = __builtin_nontemporal_load(p + (size_t)i * (B_NEUR / 2));
        uint32_t ce = (s.x != 0.0f ? 1u : 0u) | (s.y != 0.0f ? 2u : 0u);
        uint32_t co = (s.z != 0.0f ? 1u : 0u) | (s.w != 0.0f ? 2u : 0u);
        we |= ce << (2 * i);
        wo |= co << (2 * i);
    }
    uint2 wv = make_uint2(we, wo);
    *reinterpret_cast<uint2*>(codes + (size_t)kg * B_NEUR + 2 * b2) = wv;
}

// ---- phase 2: parallel speculative chunk scan, direct f32 output -----------
__global__ __launch_bounds__(256) void fmfm_scanA(
    const uint32_t* __restrict__ codes,    // [T/16][B]
    const float*    __restrict__ W,
    float*          __restrict__ out,      // [T][B]
    uint4*          __restrict__ spec)     // [C][B]: start/end states
{
    __shared__ float2 lut2[16];   // nibble -> 2 exact cur values

    const float w1  = W[0];
    const float w2  = W[1];
    const float w12 = __fadd_rn(w1, w2);

    if (threadIdx.x < 16) {
        uint32_t e = threadIdx.x;
        uint32_t c0 = e & 3u, c1 = (e >> 2) & 3u;
        float2 v;
        v.x = (c0 & 1u) ? ((c0 & 2u) ? w12 : w1) : ((c0 & 2u) ? w2 : 0.0f);
        v.y = (c1 & 1u) ? ((c1 & 2u) ? w12 : w1) : ((c1 & 2u) ? w2 : 0.0f);
        lut2[e] = v;
    }
    __syncthreads();

    const int tid = blockIdx.x * 256 + threadIdx.x;   // 0..65535
    const int b   = tid & (B_NEUR - 1);
    const int c   = tid >> 12;                        // chunk 0..15
    const int body_w0 = c * CH_W;
    const int w_start = (body_w0 >= WARM_W) ? body_w0 - WARM_W : 0;
    const int w_end   = body_w0 + CH_W;               // exclusive
    const uint32_t* cp = codes + b;

#define CLD(IDX) cp[(size_t)((IDX) < w_end ? (IDX) : (w_end - 1)) * B_NEUR]

#define DECODE2(WORD, D)                                                  \
    {                                                                     \
        _Pragma("unroll")                                                 \
        for (int _j = 0; _j < 8; ++_j)                                    \
            D[_j] = lut2[((WORD) >> (4 * _j)) & 0xFu];                    \
    }

#define STEPN(CUR)                                                        \
    {                                                                     \
        float _m = __fsub_rn(__fadd_rn(__fmul_rn(0.95f, mem), (CUR)),     \
                             rst);                                        \
        rst = (_m > 1.0f) ? 1.0f : 0.0f;                                  \
        mem = _m;                                                         \
    }

#define STEPS_(CUR, Q, K)                                                 \
    {                                                                     \
        float _m = __fsub_rn(__fadd_rn(__fmul_rn(0.95f, mem), (CUR)),     \
                             rst);                                        \
        rst = (_m > 1.0f) ? 1.0f : 0.0f;                                  \
        mem = _m;                                                         \
        __builtin_nontemporal_store(rst, (Q) + (size_t)(K) * B_NEUR);     \
    }

#define CHAIN16N(D)                                                       \
    {                                                                     \
        _Pragma("unroll")                                                 \
        for (int _j = 0; _j < 8; ++_j) { STEPN(D[_j].x) STEPN(D[_j].y) }  \
    }

#define CHAIN16S(D, WIDX)                                                 \
    {                                                                     \
        float* _q = out + (size_t)(WIDX) * 16 * B_NEUR + b;               \
        _Pragma("unroll")                                                 \
        for (int _j = 0; _j < 8; ++_j) {                                  \
            STEPS_(D[_j].x, _q, 2 * _j)                                   \
            STEPS_(D[_j].y, _q, 2 * _j + 1)                               \
        }                                                                 \
    }

    uint32_t pa = CLD(w_start);
    uint32_t pb = CLD(w_start + 1);
    uint32_t pc = CLD(w_start + 2);
    uint32_t pd = CLD(w_start + 3);

    float2 dA[8], dB[8];
    DECODE2(pa, dA)

    float mem = 0.0f, rst = 0.0f;

    // warmup: no stores (trip 0 for chunk 0)
    for (int iw = w_start; iw < body_w0; iw += 2) {
        uint32_t t0 = CLD(iw + 4);
        DECODE2(pb, dB)
        CHAIN16N(dA)
        pa = pb; pb = pc; pc = pd; pd = t0;
        uint32_t t1 = CLD(iw + 5);
        DECODE2(pb, dA)
        CHAIN16N(dB)
        pa = pb; pb = pc; pc = pd; pd = t1;
    }

    const float sm = mem;
    const float sr = rst;

    // body: direct nt stores of spike floats
    for (int iw = body_w0; iw < w_end; iw += 2) {
        uint32_t t0 = CLD(iw + 4);
        DECODE2(pb, dB)
        CHAIN16S(dA, iw)
        pa = pb; pb = pc; pc = pd; pd = t0;
        uint32_t t1 = CLD(iw + 5);
        DECODE2(pb, dA)
        CHAIN16S(dB, iw + 1)
        pa = pb; pb = pc; pc = pd; pd = t1;
    }

    uint4 sv;
    sv.x = __float_as_uint(sm);
    sv.y = (sr != 0.0f) ? 1u : 0u;
    sv.z = __float_as_uint(mem);
    sv.w = (rst != 0.0f) ? 1u : 0u;
    spec[(size_t)c * B_NEUR + b] = sv;

#undef CLD
#undef DECODE2
#undef STEPN
#undef STEPS_
#undef CHAIN16N
#undef CHAIN16S
}

// ---- phase 3: exact chaining / verification, patches f32 out ---------------
__global__ __launch_bounds__(64) void fmfm_scanB(
    const uint32_t* __restrict__ codes,
    const float*    __restrict__ W,
    float*          __restrict__ out,
    const uint4*    __restrict__ spec)
{
    const int b = blockIdx.x * 64 + threadIdx.x;
    const float w1  = W[0];
    const float w2  = W[1];
    const float w12 = __fadd_rn(w1, w2);

    float mem = 0.0f, rst = 0.0f;
    uint4 sn = spec[b];
    for (int c = 0; c < NCHUNK; ++c) {
        uint4 s = sn;
        if (c + 1 < NCHUNK) sn = spec[(size_t)(c + 1) * B_NEUR + b];
        bool ok = (s.x == __float_as_uint(mem)) &&
                  ((s.y != 0u) == (rst != 0.0f));
        if (ok) {
            mem = __uint_as_float(s.z);
            rst = s.w ? 1.0f : 0.0f;
        } else {
            // rare: recompute chunk c exactly from true state, patch out
            for (int wi = 0; wi < CH_W; ++wi) {
                uint32_t w = codes[(size_t)(c * CH_W + wi) * B_NEUR + b];
                float* q = out + (size_t)(c * CH_W + wi) * 16 * B_NEUR + b;
                #pragma unroll
                for (int j = 0; j < 16; ++j) {
                    uint32_t cc = (w >> (2 * j)) & 3u;
                    float cur = (cc & 1u) ? ((cc & 2u) ? w12 : w1)
                                          : ((cc & 2u) ? w2 : 0.0f);
                    float m = __fsub_rn(__fadd_rn(__fmul_rn(0.95f, mem), cur),
                                        rst);
                    rst = (m > 1.0f) ? 1.0f : 0.0f;
                    mem = m;
                    q[(size_t)j * B_NEUR] = rst;
                }
            }
        }
    }
}

// ---- fallback: round-1 proven fused kernel (if ws too small) ---------------
__global__ __launch_bounds__(64) void fmfm_scan_fused(
    const float2* __restrict__ sp, const float* __restrict__ W,
    float* __restrict__ out)
{
    const int b = blockIdx.x * 64 + threadIdx.x;
    const float w1 = W[0];
    const float w2 = W[1];
    const float2* p = sp + b;
    float* q = out + b;
    float mem = 0.0f, rst = 0.0f;
    #pragma unroll 8
    for (int t = 0; t < T_STEPS; ++t) {
        float2 s = p[(size_t)t * B_NEUR];
        float cur = __fadd_rn(__fmul_rn(s.x, w1), __fmul_rn(s.y, w2));
        float m = __fsub_rn(__fadd_rn(__fmul_rn(0.95f, mem), cur), rst);
        float spk = (m > 1.0f) ? 1.0f : 0.0f;
        q[(size_t)t * B_NEUR] = spk;
        mem = m;
        rst = spk;
    }
}

extern "C" void kernel_launch(void* const* d_in, const int* in_sizes, int n_in,
                              void* d_out, int out_size, void* d_ws, size_t ws_size,
                              hipStream_t stream) {
    const f4v*   sp4 = (const f4v*)d_in[0];
    const float* W   = (const float*)d_in[1];
    float*       out = (float*)d_out;

    const size_t codes_bytes = (size_t)KG * B_NEUR * 4;          // 4MB
    const size_t spec_bytes  = (size_t)NCHUNK * B_NEUR * 16;     // 1MB
    if (ws_size < codes_bytes + spec_bytes) {
        fmfm_scan_fused<<<dim3(B_NEUR / 64), dim3(64), 0, stream>>>(
            (const float2*)d_in[0], W, out);
        return;
    }
    uint32_t* codes = (uint32_t*)d_ws;
    uint4*    spec  = (uint4*)((char*)d_ws + codes_bytes);

    fmfm_compress<<<dim3(KG * (B_NEUR / 2) / 256), dim3(256), 0, stream>>>(sp4, codes);
    fmfm_scanA<<<dim3(NCHUNK * B_NEUR / 256), dim3(256), 0, stream>>>(codes, W, out, spec);
    fmfm_scanB<<<dim3(B_NEUR / 64), dim3(64), 0, stream>>>(codes, W, out, spec);
}